// Round 2
// baseline (2959.890 us; speedup 1.0000x reference)
//
#include <hip/hip_runtime.h>
#include <hip/hip_cooperative_groups.h>

namespace cg = cooperative_groups;

#define BATCHES 8
#define NPTS 2048
#define BPB 64                         // blocks per batch
#define TOTAL_BLOCKS (BATCHES * BPB)   // 512 = 2 blocks/CU * 256 CUs (LDS-limited)
#define THREADS 256
#define RPB (NPTS / BPB)               // rows per block = 32
#define RPT 4                          // rows per thread (register-blocked)
#define NSL 32                         // j-slices (lanes sharing a row-group)
#define NITERS 50

__device__ __forceinline__ float fexp2(float x) {
#if __has_builtin(__builtin_amdgcn_exp2f)
    return __builtin_amdgcn_exp2f(x);
#else
    return exp2f(x);
#endif
}

// Per-batch phase-counter barrier (monotonic counter, no reset race).
// Release/acquire via __threadfence (agent scope) around relaxed agent atomics.
__device__ __forceinline__ void batch_barrier(int* cnt, int expected) {
    __syncthreads();
    if (threadIdx.x == 0) {
        __threadfence();  // release: publish prior global stores (L2 wb on gfx95x)
        __hip_atomic_fetch_add(cnt, 1, __ATOMIC_RELAXED, __HIP_MEMORY_SCOPE_AGENT);
        while (__hip_atomic_load(cnt, __ATOMIC_RELAXED, __HIP_MEMORY_SCOPE_AGENT) < expected)
            __builtin_amdgcn_s_sleep(2);
        __threadfence();  // acquire (L2 inv)
    }
    __syncthreads();
}

__global__ __launch_bounds__(THREADS, 2)
void emd_sinkhorn(const float* __restrict__ preds, const float* __restrict__ gts,
                  float* __restrict__ out, float* __restrict__ ws)
{
    // eps = 0.005, N = M = 2048
    const float ALPHA = 288.53900817779268f;     // log2(e)/eps
    const float TWOA  = 2.f * ALPHA;
    const float EL2   = 0.0034657359027997266f;  // eps*ln2
    const float FC    = -0.038123094930796992f;  // eps*log_mu = -eps*ln(2048)

    float* fdual = ws;                       // [BATCHES*NPTS]
    float* gdual = ws + BATCHES * NPTS;      // [BATCHES*NPTS]
    int*   cnts  = (int*)(ws + 2 * BATCHES * NPTS);  // 8 counters, stride 64 ints

    const int batch = blockIdx.x & (BATCHES - 1);  // batch = blockIdx%8 -> XCD-local barrier (heuristic only)
    const int chunk = blockIdx.x >> 3;             // 0..63
    const int tid = threadIdx.x;
    const int rg  = tid >> 5;                      // row-group 0..7
    const int sl  = tid & (NSL - 1);               // j-slice 0..31
    const int row0 = chunk * RPB + rg * RPT;
    const int dbase = batch * NPTS;

    __shared__ float4 sP[NPTS];  // preds points; .w = ALPHA*(f_i - |p|^2) in g-pass
    __shared__ float4 sG[NPTS];  // gts points;   .w = ALPHA*(g_j - |q|^2) in f-pass

    const float* pb = preds + (size_t)dbase * 3;
    const float* gb = gts   + (size_t)dbase * 3;
    for (int idx = tid; idx < NPTS; idx += THREADS) {
        sP[idx] = make_float4(pb[3*idx], pb[3*idx+1], pb[3*idx+2], 0.f);
        sG[idx] = make_float4(gb[3*idx], gb[3*idx+1], gb[3*idx+2], 0.f);
    }
    for (int r = tid; r < RPB; r += THREADS)       // zero this block's g chunk
        gdual[dbase + chunk * RPB + r] = 0.f;
    if (tid == 0) cnts[batch * 64] = 0;            // redundant same-value stores: benign
    if (blockIdx.x == 0 && tid == 0) out[0] = 0.f; // d_out is poisoned 0xAA
    cg::this_grid().sync();                        // orders counter/dual/out init

    int* cnt = &cnts[batch * 64];
    int phase = 0;

    // Per-thread row constants (points never change)
    float rx[RPT], ry[RPT], rz[RPT], pp[RPT], ff[RPT];
    float gx[RPT], gy[RPT], gz[RPT], qq[RPT];
#pragma unroll
    for (int r = 0; r < RPT; ++r) {
        float4 p = sP[row0 + r];
        rx[r] = TWOA * p.x; ry[r] = TWOA * p.y; rz[r] = TWOA * p.z;
        pp[r] = p.x*p.x + p.y*p.y + p.z*p.z;
        float4 q = sG[row0 + r];
        gx[r] = TWOA * q.x; gy[r] = TWOA * q.y; gz[r] = TWOA * q.z;
        qq[r] = q.x*q.x + q.y*q.y + q.z*q.z;
    }

    float m[RPT], Ss[RPT];

    for (int it = 0; it < NITERS; ++it) {
        // ---------- f-pass: f_i = FC + |p_i|^2 - EL2*(max_j t + log2 sum 2^(t-max)) ----------
        // t_ij = a_j + 2*ALPHA*(p_i . q_j),  a_j = ALPHA*(g_j - |q_j|^2)
        for (int idx = tid; idx < NPTS; idx += THREADS) {
            float4 q = sG[idx];
            sG[idx].w = ALPHA * (gdual[dbase + idx] - (q.x*q.x + q.y*q.y + q.z*q.z));
        }
        __syncthreads();
#pragma unroll
        for (int r = 0; r < RPT; ++r) m[r] = -3.4e38f;
#pragma unroll 4
        for (int j = sl; j < NPTS; j += NSL) {
            float4 q = sG[j];
#pragma unroll
            for (int r = 0; r < RPT; ++r) {
                float t = fmaf(rx[r], q.x, fmaf(ry[r], q.y, fmaf(rz[r], q.z, q.w)));
                m[r] = fmaxf(m[r], t);
            }
        }
#pragma unroll
        for (int r = 0; r < RPT; ++r) {
#pragma unroll
            for (int d = 1; d < NSL; d <<= 1)
                m[r] = fmaxf(m[r], __shfl_xor(m[r], d, 64));
            Ss[r] = 0.f;
        }
#pragma unroll 4
        for (int j = sl; j < NPTS; j += NSL) {
            float4 q = sG[j];
#pragma unroll
            for (int r = 0; r < RPT; ++r) {
                float t = fmaf(rx[r], q.x, fmaf(ry[r], q.y, fmaf(rz[r], q.z, q.w)));
                Ss[r] += fexp2(t - m[r]);
            }
        }
#pragma unroll
        for (int r = 0; r < RPT; ++r) {
#pragma unroll
            for (int d = 1; d < NSL; d <<= 1)
                Ss[r] += __shfl_xor(Ss[r], d, 64);
            ff[r] = FC + pp[r] - EL2 * (m[r] + log2f(Ss[r]));  // all lanes hold ff
        }
        if (sl == 0) {
#pragma unroll
            for (int r = 0; r < RPT; ++r) fdual[dbase + row0 + r] = ff[r];
        }
        batch_barrier(cnt, (++phase) * BPB);

        // ---------- g-pass (mirror): g_j = FC + |q_j|^2 - EL2*(max_i t + log2 sum) ----------
        for (int idx = tid; idx < NPTS; idx += THREADS) {
            float4 p = sP[idx];
            sP[idx].w = ALPHA * (fdual[dbase + idx] - (p.x*p.x + p.y*p.y + p.z*p.z));
        }
        __syncthreads();
#pragma unroll
        for (int r = 0; r < RPT; ++r) m[r] = -3.4e38f;
#pragma unroll 4
        for (int i = sl; i < NPTS; i += NSL) {
            float4 p = sP[i];
#pragma unroll
            for (int r = 0; r < RPT; ++r) {
                float t = fmaf(gx[r], p.x, fmaf(gy[r], p.y, fmaf(gz[r], p.z, p.w)));
                m[r] = fmaxf(m[r], t);
            }
        }
#pragma unroll
        for (int r = 0; r < RPT; ++r) {
#pragma unroll
            for (int d = 1; d < NSL; d <<= 1)
                m[r] = fmaxf(m[r], __shfl_xor(m[r], d, 64));
            Ss[r] = 0.f;
        }
#pragma unroll 4
        for (int i = sl; i < NPTS; i += NSL) {
            float4 p = sP[i];
#pragma unroll
            for (int r = 0; r < RPT; ++r) {
                float t = fmaf(gx[r], p.x, fmaf(gy[r], p.y, fmaf(gz[r], p.z, p.w)));
                Ss[r] += fexp2(t - m[r]);
            }
        }
#pragma unroll
        for (int r = 0; r < RPT; ++r) {
#pragma unroll
            for (int d = 1; d < NSL; d <<= 1)
                Ss[r] += __shfl_xor(Ss[r], d, 64);
            float gval = FC + qq[r] - EL2 * (m[r] + log2f(Ss[r]));
            if (sl == 0) gdual[dbase + row0 + r] = gval;
        }
        batch_barrier(cnt, (++phase) * BPB);
    }

    // ---------- final: loss += sum_ij exp((-C+f+g)/eps) * C ----------
    // Direct (subtract-first) C here for accuracy of the P*C product.
    for (int idx = tid; idx < NPTS; idx += THREADS)
        sG[idx].w = ALPHA * gdual[dbase + idx];
    __syncthreads();

    float fa[RPT], pxr[RPT], pyr[RPT], pzr[RPT];
#pragma unroll
    for (int r = 0; r < RPT; ++r) {
        fa[r] = ALPHA * ff[r];          // ff = final f (all lanes)
        float4 p = sP[row0 + r];
        pxr[r] = p.x; pyr[r] = p.y; pzr[r] = p.z;
    }
    float acc = 0.f;
#pragma unroll 2
    for (int j = sl; j < NPTS; j += NSL) {
        float4 q = sG[j];
#pragma unroll
        for (int r = 0; r < RPT; ++r) {
            float dx = pxr[r] - q.x, dy = pyr[r] - q.y, dz = pzr[r] - q.z;
            float c  = fmaf(dx, dx, fmaf(dy, dy, dz * dz));
            float k2 = fmaf(-ALPHA, c, fa[r] + q.w);   // log2-domain kernel
            acc = fmaf(fexp2(k2), c, acc);             // P*C (underflow to 0 is correct)
        }
    }
#pragma unroll
    for (int d = 1; d < 64; d <<= 1)
        acc += __shfl_xor(acc, d, 64);
    if ((tid & 63) == 0) atomicAdd(out, acc);
}

extern "C" void kernel_launch(void* const* d_in, const int* in_sizes, int n_in,
                              void* d_out, int out_size, void* d_ws, size_t ws_size,
                              hipStream_t stream) {
    const float* preds = (const float*)d_in[0];
    const float* gts   = (const float*)d_in[1];
    float* out = (float*)d_out;
    float* ws  = (float*)d_ws;   // needs 2*8*2048 floats + 8*64 ints = ~133 KB
    void* args[] = { (void*)&preds, (void*)&gts, (void*)&out, (void*)&ws };
    hipLaunchCooperativeKernel((const void*)emd_sinkhorn, dim3(TOTAL_BLOCKS),
                               dim3(THREADS), args, 0, stream);
}